// Round 3
// baseline (44626.123 us; speedup 1.0000x reference)
//
#include <hip/hip_runtime.h>
#include <math.h>

typedef unsigned short u16;
typedef unsigned int   u32;
typedef __bf16 bf16x8 __attribute__((ext_vector_type(8)));
typedef float  f32x4  __attribute__((ext_vector_type(4)));

#define BB 256
#define TT 256
#define HD 256
#define ED 128

#define H_FLOATS (10 * 2 * BB * HD)   /* ping-pong hidden: 1,310,720 floats */
#define FLAG_INTS (12 * TT * 2)       /* flags [l+1][t][bt], l in -1..10 */

__global__ __launch_bounds__(256) void zero_state(u32* ws) {
    size_t n = (size_t)H_FLOATS + FLAG_INTS;
    size_t i = (size_t)blockIdx.x * blockDim.x + threadIdx.x;
    size_t stride = (size_t)gridDim.x * blockDim.x;
    for (; i < n; i += stride) ws[i] = 0u;
}

__device__ __forceinline__ float sigmoidf_(float v) {
    return 1.0f / (1.0f + expf(-v));
}

/* Persistent pipeline kernel.
   Grid 240 blocks = (l0:16jt + l1-4:16jt*4 + l5:8jt + l6-9:8jt*4) * 2bt.
   Block: 512 thr = 8 waves; wave w owns batch cols [bt*128+w*16, +16),
   block owns 16 j's of its layer; wave computes all 4 gates for its
   16j x 16b tile -> elementwise + c fully in registers. */
__global__ __launch_bounds__(512, 2) void lstm_persist(
    const float* __restrict__ x,
    const float* __restrict__ w_ih0_1, const float* __restrict__ w_ihr_1,
    const float* __restrict__ w_hh_1,  const float* __restrict__ b_1,
    const float* __restrict__ w_ih0_2, const float* __restrict__ w_ihr_2,
    const float* __restrict__ w_hh_2,  const float* __restrict__ b_2,
    float* __restrict__ ws, float* __restrict__ out)
{
    __shared__ __align__(16) u16 A_sh[65536];   /* 128 KiB: hi [64][strideu], lo at +64*strideu */

    /* ---- block decode ---- */
    int bid = blockIdx.x;
    int l, jt, bt;
    if (bid < 32)       { l = 0;              int r = bid;      jt = r >> 1; bt = r & 1; }
    else if (bid < 160) { int r = bid - 32;   l = 1 + (r >> 5); r &= 31;     jt = r >> 1; bt = r & 1; }
    else if (bid < 176) { int r = bid - 160;  l = 5;            jt = r >> 1; bt = r & 1; }
    else                { int r = bid - 176;  l = 6 + (r >> 4); r &= 15;     jt = r >> 1; bt = r & 1; }

    const int hd  = (l < 5) ? HD : ED;
    const int din = (l == 0) ? 32 : ((l < 6) ? 256 : 128);  /* l0: 8 real + 24 zero-pad */
    const int Kp  = din + hd;                                /* 288,512,512,512,512,384,256.. */
    const int strideu = (Kp + 63) & ~63;                     /* 320,512,...,384,256 */
    const int xw  = (l == 0) ? 8 : din;
    const int nk  = Kp >> 5;
    const int loOff = 64 * strideu;

    const float *wih, *whh, *bias;
    int wihld, whhld;
    if (l == 0)      { wih = w_ih0_1;                                whh = w_hh_1;
                       bias = b_1;                                   wihld = 8;   whhld = 256; }
    else if (l < 5)  { wih = w_ihr_1 + (size_t)(l - 1) * 1024 * 256; whh = w_hh_1 + (size_t)l * 1024 * 256;
                       bias = b_1 + l * 1024;                        wihld = 256; whhld = 256; }
    else if (l == 5) { wih = w_ih0_2;                                whh = w_hh_2;
                       bias = b_2;                                   wihld = 256; whhld = 128; }
    else             { wih = w_ihr_2 + (size_t)(l - 6) * 512 * 128;  whh = w_hh_2 + (size_t)(l - 5) * 512 * 128;
                       bias = b_2 + (l - 5) * 512;                   wihld = 128; whhld = 128; }

    const int tid = threadIdx.x;

    /* ---- one-time: convert this block's weight slice into LDS (hi/lo bf16) ----
       row = gate*16 + jl ; col k: [0,xw)=wih, [din,Kp)=whh, else 0.
       16B chunks XOR-swizzled by ((row&7)<<3) u16-chunks -> conflict-free reads. */
    {
        const int cpr = strideu >> 3;
        const int nch = 64 * cpr;
        for (int c = tid; c < nch; c += 512) {
            int row = c / cpr, cc = c - row * cpr;
            int gate = row >> 4, jl = row & 15;
            int grow = gate * hd + jt * 16 + jl;
            bf16x8 hi8, lo8;
            #pragma unroll
            for (int e = 0; e < 8; ++e) {
                int k = cc * 8 + e;
                float v = 0.0f;
                if (k < xw) v = wih[(size_t)grow * wihld + k];
                else if (k >= din && k < Kp) v = whh[(size_t)grow * whhld + (k - din)];
                __bf16 h = (__bf16)v;
                hi8[e] = h;
                lo8[e] = (__bf16)(v - (float)h);
            }
            int idx = row * strideu + ((cc * 8) ^ ((row & 7) << 3));
            *(bf16x8*)&A_sh[idx]         = hi8;
            *(bf16x8*)&A_sh[idx + loOff] = lo8;
        }
    }
    __syncthreads();

    /* ---- per-wave setup ---- */
    const int lane = tid & 63;
    const int wv   = tid >> 6;
    const int r15  = lane & 15;
    const int kq   = lane >> 4;
    const int brow = bt * 128 + wv * 16 + r15;
    const int jc0  = jt * 16 + kq * 4;

    float bgr[4][4];
    #pragma unroll
    for (int g = 0; g < 4; ++g) {
        float4 v = *(const float4*)&bias[g * hd + jc0];
        bgr[g][0] = v.x; bgr[g][1] = v.y; bgr[g][2] = v.z; bgr[g][3] = v.w;
    }

    int abase[4], axor[4];
    #pragma unroll
    for (int g = 0; g < 4; ++g) {
        int row = g * 16 + r15;
        abase[g] = row * strideu;
        axor[g]  = (row & 7) << 3;
    }

    float c0 = 0.f, c1 = 0.f, c2 = 0.f, c3 = 0.f;
    float* hbuf = ws;
    int*   flg  = (int*)(ws + H_FLOATS);
    const int myNW   = ((l < 5) ? 16 : 8) * 8;
    const int loNW   = (l > 0) ? (((l - 1 < 5) ? 16 : 8) * 8) : 0;
    const int dnNW   = (l < 9) ? (((l + 1 < 5) ? 16 : 8) * 8) : 0;

    auto waitf = [&](int l_, int t_, int target) {
        const int* p = flg + ((size_t)(l_ + 1) * TT + t_) * 2 + bt;
        while (__hip_atomic_load(p, __ATOMIC_ACQUIRE, __HIP_MEMORY_SCOPE_AGENT) < target)
            __builtin_amdgcn_s_sleep(1);
    };

    for (int t = 0; t < TT; ++t) {
        if (l > 0) waitf(l - 1, t, loNW);
        if (t > 0) waitf(l, t - 1, myNW);

        const float* hin   = (l > 0) ? (hbuf + ((size_t)(l - 1) * 2 + (t & 1)) * BB * HD) : hbuf;
        const float* hprev = hbuf + ((size_t)l * 2 + ((t & 1) ^ 1)) * BB * HD;

        f32x4 acc[4];
        #pragma unroll
        for (int g = 0; g < 4; ++g) acc[g] = (f32x4){0.f, 0.f, 0.f, 0.f};

        auto loadB = [&](int kt, float4& v0, float4& v1) {
            if (l == 0) {
                if (kt == 0) {
                    if (kq == 0) {
                        const float* xp = x + ((size_t)brow * TT + t) * 8;
                        v0 = *(const float4*)xp; v1 = *(const float4*)(xp + 4);
                    } else { v0 = make_float4(0.f,0.f,0.f,0.f); v1 = v0; }
                } else {
                    const float* p = hprev + (size_t)brow * HD + (kt * 32 - 32) + kq * 8;
                    v0 = *(const float4*)p; v1 = *(const float4*)(p + 4);
                }
            } else {
                int k0 = kt * 32 + kq * 8;
                const float* p = (k0 < din) ? (hin + (size_t)brow * HD + k0)
                                            : (hprev + (size_t)brow * HD + (k0 - din));
                v0 = *(const float4*)p; v1 = *(const float4*)(p + 4);
            }
        };

        float4 cur0, cur1;
        loadB(0, cur0, cur1);
        for (int kt = 0; kt < nk; ++kt) {
            float4 nx0, nx1;
            if (kt + 1 < nk) loadB(kt + 1, nx0, nx1);

            float f8[8] = {cur0.x, cur0.y, cur0.z, cur0.w, cur1.x, cur1.y, cur1.z, cur1.w};
            bf16x8 bh, bl;
            #pragma unroll
            for (int e = 0; e < 8; ++e) {
                __bf16 h = (__bf16)f8[e];
                bh[e] = h;
                bl[e] = (__bf16)(f8[e] - (float)h);
            }

            const int kb = kt * 32 + kq * 8;
            #pragma unroll
            for (int g = 0; g < 4; ++g) {
                int idx = abase[g] + (kb ^ axor[g]);
                bf16x8 ah = *(const bf16x8*)&A_sh[idx];
                bf16x8 al = *(const bf16x8*)&A_sh[idx + loOff];
                acc[g] = __builtin_amdgcn_mfma_f32_16x16x32_bf16(ah, bh, acc[g], 0, 0, 0);
                acc[g] = __builtin_amdgcn_mfma_f32_16x16x32_bf16(ah, bl, acc[g], 0, 0, 0);
                acc[g] = __builtin_amdgcn_mfma_f32_16x16x32_bf16(al, bh, acc[g], 0, 0, 0);
            }
            cur0 = nx0; cur1 = nx1;
        }

        /* backpressure: downstream must have consumed the parity slot we overwrite */
        if (l < 9 && t >= 2) waitf(l + 1, t - 2, dnNW);

        float hv0, hv1, hv2, hv3;
        {
            float i_, F_, g_, o_;
            i_ = sigmoidf_(acc[0][0] + bgr[0][0]); F_ = sigmoidf_(acc[1][0] + bgr[1][0]);
            g_ = tanhf   (acc[2][0] + bgr[2][0]); o_ = sigmoidf_(acc[3][0] + bgr[3][0]);
            c0 = fmaf(F_, c0, i_ * g_); hv0 = o_ * tanhf(c0);
            i_ = sigmoidf_(acc[0][1] + bgr[0][1]); F_ = sigmoidf_(acc[1][1] + bgr[1][1]);
            g_ = tanhf   (acc[2][1] + bgr[2][1]); o_ = sigmoidf_(acc[3][1] + bgr[3][1]);
            c1 = fmaf(F_, c1, i_ * g_); hv1 = o_ * tanhf(c1);
            i_ = sigmoidf_(acc[0][2] + bgr[0][2]); F_ = sigmoidf_(acc[1][2] + bgr[1][2]);
            g_ = tanhf   (acc[2][2] + bgr[2][2]); o_ = sigmoidf_(acc[3][2] + bgr[3][2]);
            c2 = fmaf(F_, c2, i_ * g_); hv2 = o_ * tanhf(c2);
            i_ = sigmoidf_(acc[0][3] + bgr[0][3]); F_ = sigmoidf_(acc[1][3] + bgr[1][3]);
            g_ = tanhf   (acc[2][3] + bgr[2][3]); o_ = sigmoidf_(acc[3][3] + bgr[3][3]);
            c3 = fmaf(F_, c3, i_ * g_); hv3 = o_ * tanhf(c3);
        }
        float4 hv4 = make_float4(hv0, hv1, hv2, hv3);
        float* hout = hbuf + ((size_t)l * 2 + (t & 1)) * BB * HD;
        *(float4*)&hout[(size_t)brow * HD + jc0] = hv4;
        if (l == 9 && t == TT - 1)
            *(float4*)&out[(size_t)brow * ED + jc0] = hv4;

        __threadfence();
        if (lane == 0)
            __hip_atomic_fetch_add(flg + ((size_t)(l + 1) * TT + t) * 2 + bt, 1,
                                   __ATOMIC_RELEASE, __HIP_MEMORY_SCOPE_AGENT);
    }
}

extern "C" void kernel_launch(void* const* d_in, const int* in_sizes, int n_in,
                              void* d_out, int out_size, void* d_ws, size_t ws_size,
                              hipStream_t stream) {
    const float* x       = (const float*)d_in[0];
    const float* w_ih0_1 = (const float*)d_in[1];
    const float* w_ihr_1 = (const float*)d_in[2];
    const float* w_hh_1  = (const float*)d_in[3];
    const float* b_1     = (const float*)d_in[4];
    const float* w_ih0_2 = (const float*)d_in[5];
    const float* w_ihr_2 = (const float*)d_in[6];
    const float* w_hh_2  = (const float*)d_in[7];
    const float* b_2     = (const float*)d_in[8];
    float* ws  = (float*)d_ws;
    float* out = (float*)d_out;

    hipLaunchKernelGGL(zero_state, dim3(256), dim3(256), 0, stream, (u32*)ws);
    hipLaunchKernelGGL(lstm_persist, dim3(240), dim3(512), 0, stream,
                       x, w_ih0_1, w_ihr_1, w_hh_1, b_1,
                       w_ih0_2, w_ihr_2, w_hh_2, b_2, ws, out);
}

// Round 4
// 5037.854 us; speedup vs baseline: 8.8582x; 8.8582x over previous
//
#include <hip/hip_runtime.h>
#include <math.h>

typedef unsigned short u16;
typedef unsigned int   u32;
typedef __bf16 bf16x8 __attribute__((ext_vector_type(8)));
typedef float  f32x4  __attribute__((ext_vector_type(4)));

#define BB 256
#define TT 256
#define HD 256
#define ED 128
#define WAVE_STEPS (TT + 10 - 1)   /* 265 */

#define H_FLOATS (10 * 2 * BB * HD)         /* 1,310,720 */
#define C_FLOATS (10 * BB * HD)             /*   655,360 */
#define STATE_FLOATS (H_FLOATS + C_FLOATS)  /* 1,966,080 floats = 7.86 MB */

/* u16 offsets of each layer's swizzled-fragment weight region */
__constant__ size_t g_woff[10] = {0ul,589824ul,1638400ul,2686976ul,3735552ul,
                                  4784128ul,5177344ul,5439488ul,5701632ul,5963776ul};
/* chunk (8-elem) boundaries per layer for the conversion kernel */
__constant__ int g_cb[11] = {0,73728,204800,335872,466944,598016,
                             647168,679936,712704,745472,778240};

__device__ __forceinline__ float sigmoidf_(float v) {
    return 1.0f / (1.0f + expf(-v));
}

__global__ __launch_bounds__(256) void zero_state(float* ws) {
    float4* p = (float4*)ws;
    int n = STATE_FLOATS / 4;
    for (int i = blockIdx.x * blockDim.x + threadIdx.x; i < n;
         i += gridDim.x * blockDim.x)
        p[i] = make_float4(0.f, 0.f, 0.f, 0.f);
}

/* Convert all layers' weights into bf16 hi/lo, pre-swizzled to MFMA fragment
   order: chunk = (((jt*4+g)*2+p)*nk + kt)*64 + lane ; elem e -> k=kt*32+kq*8+e,
   row = g*hd + jt*16 + (lane&15). */
__global__ __launch_bounds__(256) void conv_all(
    const float* __restrict__ w_ih0_1, const float* __restrict__ w_ihr_1,
    const float* __restrict__ w_hh_1,
    const float* __restrict__ w_ih0_2, const float* __restrict__ w_ihr_2,
    const float* __restrict__ w_hh_2,
    float* __restrict__ ws)
{
    __bf16* dst0 = (__bf16*)(ws + STATE_FLOATS);
    const int nch = 778240;
    for (int ci = blockIdx.x * blockDim.x + threadIdx.x; ci < nch;
         ci += gridDim.x * blockDim.x) {
        int l = 0;
        while (ci >= g_cb[l + 1]) ++l;
        int di = ci - g_cb[l];

        const int hd  = (l < 5) ? 256 : 128;
        const int din = (l == 0) ? 32 : ((l < 6) ? 256 : 128);
        const int xw  = (l == 0) ? 8 : din;
        const int Kp  = din + hd;
        const int nk  = Kp >> 5;

        const float *wih, *whh; int wihld, whhld;
        if (l == 0)      { wih = w_ih0_1;                                whh = w_hh_1;
                           wihld = 8;   whhld = 256; }
        else if (l < 5)  { wih = w_ihr_1 + (size_t)(l - 1) * 1024 * 256; whh = w_hh_1 + (size_t)l * 1024 * 256;
                           wihld = 256; whhld = 256; }
        else if (l == 5) { wih = w_ih0_2;                                whh = w_hh_2;
                           wihld = 256; whhld = 128; }
        else             { wih = w_ihr_2 + (size_t)(l - 6) * 512 * 128;  whh = w_hh_2 + (size_t)(l - 5) * 512 * 128;
                           wihld = 128; whhld = 128; }

        int lane = di & 63;
        int rem  = di >> 6;
        int kt   = rem % nk;
        int rem2 = rem / nk;
        int p    = rem2 & 1;
        int g    = (rem2 >> 1) & 3;
        int jt   = rem2 >> 3;
        int r15  = lane & 15, kq = lane >> 4;
        int row  = g * hd + jt * 16 + r15;

        bf16x8 o8;
        #pragma unroll
        for (int e = 0; e < 8; ++e) {
            int k = kt * 32 + kq * 8 + e;
            float v = 0.0f;
            if (k < xw) v = wih[(size_t)row * wihld + k];
            else if (k >= din && k < Kp) v = whh[(size_t)row * whhld + (k - din)];
            __bf16 h = (__bf16)v;
            o8[e] = p ? (__bf16)(v - (float)h) : h;
        }
        *(bf16x8*)(dst0 + g_woff[l] + (size_t)di * 8) = o8;
    }
}

/* One wavefront step: (l, t=w-l) for all valid layers.
   Grid 240: l0-4: 32 blocks each (16 jt x 2 bt); l5-9: 16 each (8 jt x 2 bt).
   Block 512 thr = 8 waves; wave wv handles batch [bt*128+wv*16, +16) x 16 j
   x all 4 gates. No LDS, no barriers; A streamed in fragment order. */
__global__ __launch_bounds__(512) void lstm_step(
    int w,
    const float* __restrict__ x,
    const float* __restrict__ b_1, const float* __restrict__ b_2,
    float* __restrict__ ws, float* __restrict__ out)
{
    int bid = blockIdx.x;
    int l, jt, bt;
    if (bid < 160) { l = bid >> 5; int r = bid & 31; jt = r >> 1; bt = r & 1; }
    else { int b2 = bid - 160; l = 5 + (b2 >> 4); int r = b2 & 15; jt = r >> 1; bt = r & 1; }
    int t = w - l;
    if (t < 0 || t >= TT) return;

    const int hd  = (l < 5) ? 256 : 128;
    const int din = (l == 0) ? 32 : ((l < 6) ? 256 : 128);
    const int nk  = (din + hd) >> 5;
    const float* bias = (l < 5) ? (b_1 + l * 1024) : (b_2 + (l - 5) * 512);

    float* hbuf = ws;
    float* cbuf = ws + H_FLOATS;
    const float* hin   = hbuf + ((size_t)(l - 1) * 2 + (t & 1)) * BB * HD;   /* l>0 */
    const float* hprev = hbuf + ((size_t)l * 2 + ((t & 1) ^ 1)) * BB * HD;
    float* hout = hbuf + ((size_t)l * 2 + (t & 1)) * BB * HD;
    float* crow = cbuf + (size_t)l * BB * HD;

    const int tid  = threadIdx.x;
    const int lane = tid & 63;
    const int wv   = tid >> 6;
    const int r15  = lane & 15;
    const int kq   = lane >> 4;
    const int brow = bt * 128 + wv * 16 + r15;
    const int j0   = jt * 16 + kq * 4;

    /* A fragment streams: 8 wave-uniform offsets + per-lane base */
    const u16* awt = (const u16*)(ws + STATE_FLOATS) + g_woff[l]
                     + (size_t)jt * 8 * nk * 512 + lane * 8;
    const int s0h = 0 * nk * 512, s0l = 1 * nk * 512;
    const int s1h = 2 * nk * 512, s1l = 3 * nk * 512;
    const int s2h = 4 * nk * 512, s2l = 5 * nk * 512;
    const int s3h = 6 * nk * 512, s3l = 7 * nk * 512;

    auto LDA = [&](int s, int kt) -> bf16x8 {
        return *(const bf16x8*)(awt + s + (size_t)kt * 512);
    };
    auto loadB = [&](int kt, float4& v0, float4& v1) {
        if (l == 0) {
            if (kt == 0) {
                if (kq == 0) {
                    const float* xp = x + ((size_t)brow * TT + t) * 8;
                    v0 = *(const float4*)xp; v1 = *(const float4*)(xp + 4);
                } else { v0 = make_float4(0.f, 0.f, 0.f, 0.f); v1 = v0; }
            } else {
                const float* p = hprev + (size_t)brow * HD + kt * 32 - 32 + kq * 8;
                v0 = *(const float4*)p; v1 = *(const float4*)(p + 4);
            }
        } else {
            int k0 = kt * 32 + kq * 8;
            const float* p = (k0 < din) ? (hin + (size_t)brow * HD + k0)
                                        : (hprev + (size_t)brow * HD + (k0 - din));
            v0 = *(const float4*)p; v1 = *(const float4*)(p + 4);
        }
    };

    f32x4 acc0 = {0.f,0.f,0.f,0.f}, acc1 = {0.f,0.f,0.f,0.f};
    f32x4 acc2 = {0.f,0.f,0.f,0.f}, acc3 = {0.f,0.f,0.f,0.f};

    bf16x8 a0h = LDA(s0h,0), a0l = LDA(s0l,0), a1h = LDA(s1h,0), a1l = LDA(s1l,0);
    bf16x8 a2h = LDA(s2h,0), a2l = LDA(s2l,0), a3h = LDA(s3h,0), a3l = LDA(s3l,0);
    float4 bc0, bc1;
    loadB(0, bc0, bc1);

    for (int kt = 0; kt < nk; ++kt) {
        int ktn = kt + 1;
        bf16x8 n0h, n0l, n1h, n1l, n2h, n2l, n3h, n3l;
        float4 bn0, bn1;
        if (ktn < nk) {
            n0h = LDA(s0h,ktn); n0l = LDA(s0l,ktn);
            n1h = LDA(s1h,ktn); n1l = LDA(s1l,ktn);
            n2h = LDA(s2h,ktn); n2l = LDA(s2l,ktn);
            n3h = LDA(s3h,ktn); n3l = LDA(s3l,ktn);
            loadB(ktn, bn0, bn1);
        }

        /* in-register hi/lo split of B */
        bf16x8 bh, bl;
        {
            __bf16 h;
            h = (__bf16)bc0.x; bh[0] = h; bl[0] = (__bf16)(bc0.x - (float)h);
            h = (__bf16)bc0.y; bh[1] = h; bl[1] = (__bf16)(bc0.y - (float)h);
            h = (__bf16)bc0.z; bh[2] = h; bl[2] = (__bf16)(bc0.z - (float)h);
            h = (__bf16)bc0.w; bh[3] = h; bl[3] = (__bf16)(bc0.w - (float)h);
            h = (__bf16)bc1.x; bh[4] = h; bl[4] = (__bf16)(bc1.x - (float)h);
            h = (__bf16)bc1.y; bh[5] = h; bl[5] = (__bf16)(bc1.y - (float)h);
            h = (__bf16)bc1.z; bh[6] = h; bl[6] = (__bf16)(bc1.z - (float)h);
            h = (__bf16)bc1.w; bh[7] = h; bl[7] = (__bf16)(bc1.w - (float)h);
        }

        acc0 = __builtin_amdgcn_mfma_f32_16x16x32_bf16(a0h, bh, acc0, 0, 0, 0);
        acc1 = __builtin_amdgcn_mfma_f32_16x16x32_bf16(a1h, bh, acc1, 0, 0, 0);
        acc2 = __builtin_amdgcn_mfma_f32_16x16x32_bf16(a2h, bh, acc2, 0, 0, 0);
        acc3 = __builtin_amdgcn_mfma_f32_16x16x32_bf16(a3h, bh, acc3, 0, 0, 0);
        acc0 = __builtin_amdgcn_mfma_f32_16x16x32_bf16(a0h, bl, acc0, 0, 0, 0);
        acc1 = __builtin_amdgcn_mfma_f32_16x16x32_bf16(a1h, bl, acc1, 0, 0, 0);
        acc2 = __builtin_amdgcn_mfma_f32_16x16x32_bf16(a2h, bl, acc2, 0, 0, 0);
        acc3 = __builtin_amdgcn_mfma_f32_16x16x32_bf16(a3h, bl, acc3, 0, 0, 0);
        acc0 = __builtin_amdgcn_mfma_f32_16x16x32_bf16(a0l, bh, acc0, 0, 0, 0);
        acc1 = __builtin_amdgcn_mfma_f32_16x16x32_bf16(a1l, bh, acc1, 0, 0, 0);
        acc2 = __builtin_amdgcn_mfma_f32_16x16x32_bf16(a2l, bh, acc2, 0, 0, 0);
        acc3 = __builtin_amdgcn_mfma_f32_16x16x32_bf16(a3l, bh, acc3, 0, 0, 0);

        a0h = n0h; a0l = n0l; a1h = n1h; a1l = n1l;
        a2h = n2h; a2l = n2l; a3h = n3h; a3l = n3l;
        bc0 = bn0; bc1 = bn1;
    }

    /* epilogue: bias + activations + c/h update, all register-local */
    float4 bi = *(const float4*)&bias[0 * hd + j0];
    float4 bf = *(const float4*)&bias[1 * hd + j0];
    float4 bg = *(const float4*)&bias[2 * hd + j0];
    float4 bo = *(const float4*)&bias[3 * hd + j0];
    float4 cv = *(const float4*)&crow[(size_t)brow * HD + j0];

    float4 cn, hv;
    {
        float i_, f_, g_, o_;
        i_ = sigmoidf_(acc0[0] + bi.x); f_ = sigmoidf_(acc1[0] + bf.x);
        g_ = tanhf   (acc2[0] + bg.x); o_ = sigmoidf_(acc3[0] + bo.x);
        cn.x = fmaf(f_, cv.x, i_ * g_); hv.x = o_ * tanhf(cn.x);
        i_ = sigmoidf_(acc0[1] + bi.y); f_ = sigmoidf_(acc1[1] + bf.y);
        g_ = tanhf   (acc2[1] + bg.y); o_ = sigmoidf_(acc3[1] + bo.y);
        cn.y = fmaf(f_, cv.y, i_ * g_); hv.y = o_ * tanhf(cn.y);
        i_ = sigmoidf_(acc0[2] + bi.z); f_ = sigmoidf_(acc1[2] + bf.z);
        g_ = tanhf   (acc2[2] + bg.z); o_ = sigmoidf_(acc3[2] + bo.z);
        cn.z = fmaf(f_, cv.z, i_ * g_); hv.z = o_ * tanhf(cn.z);
        i_ = sigmoidf_(acc0[3] + bi.w); f_ = sigmoidf_(acc1[3] + bf.w);
        g_ = tanhf   (acc2[3] + bg.w); o_ = sigmoidf_(acc3[3] + bo.w);
        cn.w = fmaf(f_, cv.w, i_ * g_); hv.w = o_ * tanhf(cn.w);
    }

    *(float4*)&crow[(size_t)brow * HD + j0] = cn;
    *(float4*)&hout[(size_t)brow * HD + j0] = hv;
    if (l == 9 && t == TT - 1)
        *(float4*)&out[(size_t)brow * ED + j0] = hv;
}

extern "C" void kernel_launch(void* const* d_in, const int* in_sizes, int n_in,
                              void* d_out, int out_size, void* d_ws, size_t ws_size,
                              hipStream_t stream) {
    const float* x       = (const float*)d_in[0];
    const float* w_ih0_1 = (const float*)d_in[1];
    const float* w_ihr_1 = (const float*)d_in[2];
    const float* w_hh_1  = (const float*)d_in[3];
    const float* b_1     = (const float*)d_in[4];
    const float* w_ih0_2 = (const float*)d_in[5];
    const float* w_ihr_2 = (const float*)d_in[6];
    const float* w_hh_2  = (const float*)d_in[7];
    const float* b_2     = (const float*)d_in[8];
    float* ws  = (float*)d_ws;
    float* out = (float*)d_out;

    hipLaunchKernelGGL(zero_state, dim3(512), dim3(256), 0, stream, ws);
    hipLaunchKernelGGL(conv_all, dim3(1024), dim3(256), 0, stream,
                       w_ih0_1, w_ihr_1, w_hh_1, w_ih0_2, w_ihr_2, w_hh_2, ws);
    for (int w = 0; w < WAVE_STEPS; ++w) {
        hipLaunchKernelGGL(lstm_step, dim3(240), dim3(512), 0, stream,
                           w, x, b_1, b_2, ws, out);
    }
}

// Round 5
// 3955.962 us; speedup vs baseline: 11.2807x; 1.2735x over previous
//
#include <hip/hip_runtime.h>
#include <math.h>

typedef unsigned short u16;
typedef unsigned int   u32;
typedef __bf16 bf16x8 __attribute__((ext_vector_type(8)));
typedef float  f32x4  __attribute__((ext_vector_type(4)));

#define BB 256
#define TT 256
#define HD 256
#define ED 128
#define NSTEPS 265

#define H_FLOATS (10 * 2 * BB * HD)      /* 1,310,720 floats: h ping-pong */
#define CTR_U32  256                      /* 8 counters, 128B-padded */
#define WTS_OFF  (H_FLOATS + CTR_U32)     /* float-index of weight region */

/* u16 offsets of each layer's fragment-ordered weight region (round-4 layout) */
__constant__ size_t g_woff[10] = {0ul,589824ul,1638400ul,2686976ul,3735552ul,
                                  4784128ul,5177344ul,5439488ul,5701632ul,5963776ul};
__constant__ int g_cb[11] = {0,73728,204800,335872,466944,598016,
                             647168,679936,712704,745472,778240};

__device__ __forceinline__ float sigmoidf_(float v) {
    return 1.0f / (1.0f + expf(-v));
}

__global__ __launch_bounds__(256) void zero_state(u32* ws) {
    int n = H_FLOATS + CTR_U32;
    for (int i = blockIdx.x * blockDim.x + threadIdx.x; i < n;
         i += gridDim.x * blockDim.x) ws[i] = 0u;
}

/* Convert all layers' weights into bf16 hi/lo, fragment order (as round 4):
   chunk = (((jt*4+g)*2+p)*nk + kt)*64 + lane ; elem e -> k=kt*32+kq*8+e,
   row = g*hd + jt*16 + (lane&15). */
__global__ __launch_bounds__(256) void conv_all(
    const float* __restrict__ w_ih0_1, const float* __restrict__ w_ihr_1,
    const float* __restrict__ w_hh_1,
    const float* __restrict__ w_ih0_2, const float* __restrict__ w_ihr_2,
    const float* __restrict__ w_hh_2,
    float* __restrict__ ws)
{
    __bf16* dst0 = (__bf16*)(ws + WTS_OFF);
    const int nch = 778240;
    for (int ci = blockIdx.x * blockDim.x + threadIdx.x; ci < nch;
         ci += gridDim.x * blockDim.x) {
        int l = 0;
        while (ci >= g_cb[l + 1]) ++l;
        int di = ci - g_cb[l];

        const int hd  = (l < 5) ? 256 : 128;
        const int din = (l == 0) ? 32 : ((l < 6) ? 256 : 128);
        const int xw  = (l == 0) ? 8 : din;
        const int Kp  = din + hd;
        const int nk  = Kp >> 5;

        const float *wih, *whh; int wihld, whhld;
        if (l == 0)      { wih = w_ih0_1;                                whh = w_hh_1;
                           wihld = 8;   whhld = 256; }
        else if (l < 5)  { wih = w_ihr_1 + (size_t)(l - 1) * 1024 * 256; whh = w_hh_1 + (size_t)l * 1024 * 256;
                           wihld = 256; whhld = 256; }
        else if (l == 5) { wih = w_ih0_2;                                whh = w_hh_2;
                           wihld = 256; whhld = 128; }
        else             { wih = w_ihr_2 + (size_t)(l - 6) * 512 * 128;  whh = w_hh_2 + (size_t)(l - 5) * 512 * 128;
                           wihld = 128; whhld = 128; }

        int lane = di & 63;
        int rem  = di >> 6;
        int kt   = rem % nk;
        int rem2 = rem / nk;
        int p    = rem2 & 1;
        int g    = (rem2 >> 1) & 3;
        int jt   = rem2 >> 3;
        int r15  = lane & 15, kq = lane >> 4;
        int row  = g * hd + jt * 16 + r15;

        bf16x8 o8;
        #pragma unroll
        for (int e = 0; e < 8; ++e) {
            int k = kt * 32 + kq * 8 + e;
            float v = 0.0f;
            if (k < xw) v = wih[(size_t)row * wihld + k];
            else if (k >= din && k < Kp) v = whh[(size_t)row * whhld + (k - din)];
            __bf16 h = (__bf16)v;
            o8[e] = p ? (__bf16)(v - (float)h) : h;
        }
        *(bf16x8*)(dst0 + g_woff[l] + (size_t)di * 8) = o8;
    }
}

/* Persistent kernel: 240 blocks (1/CU), 512 thr = 8 waves.
   Block owns (l, 16 j, 128 batch) for all 265 wavefront steps.
   Weights in LDS (once). c in registers. h handoff: write-through
   relaxed-agent atomic stores; barrier: 8 padded counters, relaxed add +
   relaxed poll + one acquire-inv per block per step. */
__global__ __launch_bounds__(512, 2) void lstm_persist(
    const float* __restrict__ x,
    const float* __restrict__ b_1, const float* __restrict__ b_2,
    float* __restrict__ ws, float* __restrict__ out)
{
    __shared__ __align__(16) u16 A_lds[65536];   /* 128 KiB */

    const int bid = blockIdx.x;
    int l, jt, bt;
    if (bid < 32)       { l = 0;             jt = bid >> 1;              bt = bid & 1; }
    else if (bid < 160) { int r = bid - 32;  l = 1 + (r >> 5); r &= 31;  jt = r >> 1; bt = r & 1; }
    else if (bid < 176) { int r = bid - 160; l = 5;                      jt = r >> 1; bt = r & 1; }
    else                { int r = bid - 176; l = 6 + (r >> 4); r &= 15;  jt = r >> 1; bt = r & 1; }

    const int hd  = (l < 5) ? 256 : 128;
    const int din = (l == 0) ? 32 : ((l < 6) ? 256 : 128);
    const int nk  = (din + hd) >> 5;
    const float* bias = (l < 5) ? (b_1 + l * 1024) : (b_2 + (l - 5) * 512);

    float* hbuf = ws;
    u32*   ctr  = (u32*)(ws + H_FLOATS);
    const u16* wt = (const u16*)(ws + WTS_OFF);

    const int tid  = threadIdx.x;
    const int lane = tid & 63;
    const int wv   = tid >> 6;
    const int r15  = lane & 15;
    const int kq   = lane >> 4;
    const int brow = bt * 128 + wv * 16 + r15;
    const int j0   = jt * 16 + kq * 4;

    /* ---- one-time: copy this block's weight slice into LDS ---- */
    {
        const uint4* src = (const uint4*)(wt + g_woff[l] + (size_t)jt * 8 * nk * 512);
        uint4* dst = (uint4*)A_lds;
        const int n4 = nk * 512;
        for (int i = tid; i < n4; i += 512) dst[i] = src[i];
    }
    __syncthreads();

    /* bias into registers */
    float bgr[4][4];
    #pragma unroll
    for (int g = 0; g < 4; ++g) {
        float4 v = *(const float4*)&bias[g * hd + j0];
        bgr[g][0] = v.x; bgr[g][1] = v.y; bgr[g][2] = v.z; bgr[g][3] = v.w;
    }

    /* LDS fragment offsets (u16 units): stream s=(g*2+p) at (s*nk+kt)*512+lane*8 */
    int offH[4], offL[4];
    #pragma unroll
    for (int g = 0; g < 4; ++g) {
        offH[g] = (g * 2)     * nk * 512 + lane * 8;
        offL[g] = (g * 2 + 1) * nk * 512 + lane * 8;
    }

    float4 cv = make_float4(0.f, 0.f, 0.f, 0.f);   /* cell state, registers */

    for (int w = 0; w < NSTEPS; ++w) {
        const int t = w - l;
        if (t >= 0 && t < TT) {
            const float* hin   = hbuf + ((size_t)(l - 1) * 2 + (t & 1)) * BB * HD;
            const float* hprev = hbuf + ((size_t)l * 2 + ((t & 1) ^ 1)) * BB * HD;
            float* hout = hbuf + ((size_t)l * 2 + (t & 1)) * BB * HD;

            auto loadB = [&](int kt, float4& v0, float4& v1) {
                if (l == 0) {
                    if (kt == 0) {
                        if (kq == 0) {
                            const float* xp = x + ((size_t)brow * TT + t) * 8;
                            v0 = *(const float4*)xp; v1 = *(const float4*)(xp + 4);
                        } else { v0 = make_float4(0.f,0.f,0.f,0.f); v1 = v0; }
                    } else {
                        const float* p = hprev + (size_t)brow * HD + kt * 32 - 32 + kq * 8;
                        v0 = *(const float4*)p; v1 = *(const float4*)(p + 4);
                    }
                } else {
                    int k0 = kt * 32 + kq * 8;
                    const float* p = (k0 < din) ? (hin + (size_t)brow * HD + k0)
                                                : (hprev + (size_t)brow * HD + (k0 - din));
                    v0 = *(const float4*)p; v1 = *(const float4*)(p + 4);
                }
            };

            f32x4 acc0 = {0.f,0.f,0.f,0.f}, acc1 = {0.f,0.f,0.f,0.f};
            f32x4 acc2 = {0.f,0.f,0.f,0.f}, acc3 = {0.f,0.f,0.f,0.f};

            float4 cA, cB, nA, nB;
            loadB(0, cA, cB);
            if (nk > 1) loadB(1, nA, nB);

            for (int kt = 0; kt < nk; ++kt) {
                float4 fA, fB;
                if (kt + 2 < nk) loadB(kt + 2, fA, fB);

                bf16x8 bh, bl;
                {
                    float f8[8] = {cA.x, cA.y, cA.z, cA.w, cB.x, cB.y, cB.z, cB.w};
                    #pragma unroll
                    for (int e = 0; e < 8; ++e) {
                        __bf16 h = (__bf16)f8[e];
                        bh[e] = h;
                        bl[e] = (__bf16)(f8[e] - (float)h);
                    }
                }

                const int kof = kt * 512;
                bf16x8 a0h = *(const bf16x8*)&A_lds[offH[0] + kof];
                bf16x8 a1h = *(const bf16x8*)&A_lds[offH[1] + kof];
                bf16x8 a2h = *(const bf16x8*)&A_lds[offH[2] + kof];
                bf16x8 a3h = *(const bf16x8*)&A_lds[offH[3] + kof];
                bf16x8 a0l = *(const bf16x8*)&A_lds[offL[0] + kof];
                bf16x8 a1l = *(const bf16x8*)&A_lds[offL[1] + kof];
                bf16x8 a2l = *(const bf16x8*)&A_lds[offL[2] + kof];
                bf16x8 a3l = *(const bf16x8*)&A_lds[offL[3] + kof];

                acc0 = __builtin_amdgcn_mfma_f32_16x16x32_bf16(a0h, bh, acc0, 0, 0, 0);
                acc1 = __builtin_amdgcn_mfma_f32_16x16x32_bf16(a1h, bh, acc1, 0, 0, 0);
                acc2 = __builtin_amdgcn_mfma_f32_16x16x32_bf16(a2h, bh, acc2, 0, 0, 0);
                acc3 = __builtin_amdgcn_mfma_f32_16x16x32_bf16(a3h, bh, acc3, 0, 0, 0);
                acc0 = __builtin_amdgcn_mfma_f32_16x16x32_bf16(a0h, bl, acc0, 0, 0, 0);
                acc1 = __builtin_amdgcn_mfma_f32_16x16x32_bf16(a1h, bl, acc1, 0, 0, 0);
                acc2 = __builtin_amdgcn_mfma_f32_16x16x32_bf16(a2h, bl, acc2, 0, 0, 0);
                acc3 = __builtin_amdgcn_mfma_f32_16x16x32_bf16(a3h, bl, acc3, 0, 0, 0);
                acc0 = __builtin_amdgcn_mfma_f32_16x16x32_bf16(a0l, bh, acc0, 0, 0, 0);
                acc1 = __builtin_amdgcn_mfma_f32_16x16x32_bf16(a1l, bh, acc1, 0, 0, 0);
                acc2 = __builtin_amdgcn_mfma_f32_16x16x32_bf16(a2l, bh, acc2, 0, 0, 0);
                acc3 = __builtin_amdgcn_mfma_f32_16x16x32_bf16(a3l, bh, acc3, 0, 0, 0);

                cA = nA; cB = nB; nA = fA; nB = fB;
            }

            /* epilogue: bias + activations + register c update */
            float4 hv;
            {
                float i_, f_, g_, o_;
                i_ = sigmoidf_(acc0[0] + bgr[0][0]); f_ = sigmoidf_(acc1[0] + bgr[1][0]);
                g_ = tanhf   (acc2[0] + bgr[2][0]); o_ = sigmoidf_(acc3[0] + bgr[3][0]);
                cv.x = fmaf(f_, cv.x, i_ * g_); hv.x = o_ * tanhf(cv.x);
                i_ = sigmoidf_(acc0[1] + bgr[0][1]); f_ = sigmoidf_(acc1[1] + bgr[1][1]);
                g_ = tanhf   (acc2[1] + bgr[2][1]); o_ = sigmoidf_(acc3[1] + bgr[3][1]);
                cv.y = fmaf(f_, cv.y, i_ * g_); hv.y = o_ * tanhf(cv.y);
                i_ = sigmoidf_(acc0[2] + bgr[0][2]); f_ = sigmoidf_(acc1[2] + bgr[1][2]);
                g_ = tanhf   (acc2[2] + bgr[2][2]); o_ = sigmoidf_(acc3[2] + bgr[3][2]);
                cv.z = fmaf(f_, cv.z, i_ * g_); hv.z = o_ * tanhf(cv.z);
                i_ = sigmoidf_(acc0[3] + bgr[0][3]); f_ = sigmoidf_(acc1[3] + bgr[1][3]);
                g_ = tanhf   (acc2[3] + bgr[2][3]); o_ = sigmoidf_(acc3[3] + bgr[3][3]);
                cv.w = fmaf(f_, cv.w, i_ * g_); hv.w = o_ * tanhf(cv.w);
            }

            /* write-through h stores (agent scope -> L3, no dirty L2) */
            u32* hp = (u32*)(hout + (size_t)brow * HD + j0);
            __hip_atomic_store(hp + 0, __float_as_uint(hv.x), __ATOMIC_RELAXED, __HIP_MEMORY_SCOPE_AGENT);
            __hip_atomic_store(hp + 1, __float_as_uint(hv.y), __ATOMIC_RELAXED, __HIP_MEMORY_SCOPE_AGENT);
            __hip_atomic_store(hp + 2, __float_as_uint(hv.z), __ATOMIC_RELAXED, __HIP_MEMORY_SCOPE_AGENT);
            __hip_atomic_store(hp + 3, __float_as_uint(hv.w), __ATOMIC_RELAXED, __HIP_MEMORY_SCOPE_AGENT);

            if (l == 9 && t == TT - 1)
                *(float4*)&out[(size_t)brow * ED + j0] = hv;
        }

        /* ---- grid barrier: syncthreads drains vmcnt; tid0 arrives+polls ---- */
        __syncthreads();
        if (tid == 0) {
            __hip_atomic_fetch_add(&ctr[(bid & 7) * 32], 1u,
                                   __ATOMIC_RELAXED, __HIP_MEMORY_SCOPE_AGENT);
            const u32 tgt = (u32)(30 * (w + 1));
            for (int it = 0; it < (1 << 22); ++it) {
                bool ok = true;
                #pragma unroll
                for (int r = 0; r < 8; ++r)
                    ok &= (__hip_atomic_load(&ctr[r * 32], __ATOMIC_RELAXED,
                                             __HIP_MEMORY_SCOPE_AGENT) >= tgt);
                if (ok) break;
                __builtin_amdgcn_s_sleep(2);
            }
            __builtin_amdgcn_fence(__ATOMIC_ACQUIRE, "agent");  /* inv, no writeback */
        }
        __syncthreads();
    }
}

extern "C" void kernel_launch(void* const* d_in, const int* in_sizes, int n_in,
                              void* d_out, int out_size, void* d_ws, size_t ws_size,
                              hipStream_t stream) {
    const float* x       = (const float*)d_in[0];
    const float* w_ih0_1 = (const float*)d_in[1];
    const float* w_ihr_1 = (const float*)d_in[2];
    const float* w_hh_1  = (const float*)d_in[3];
    const float* b_1     = (const float*)d_in[4];
    const float* w_ih0_2 = (const float*)d_in[5];
    const float* w_ihr_2 = (const float*)d_in[6];
    const float* w_hh_2  = (const float*)d_in[7];
    const float* b_2     = (const float*)d_in[8];
    float* ws  = (float*)d_ws;
    float* out = (float*)d_out;

    hipLaunchKernelGGL(zero_state, dim3(256), dim3(256), 0, stream, (u32*)ws);
    hipLaunchKernelGGL(conv_all, dim3(1024), dim3(256), 0, stream,
                       w_ih0_1, w_ihr_1, w_hh_1, w_ih0_2, w_ihr_2, w_hh_2, ws);
    hipLaunchKernelGGL(lstm_persist, dim3(240), dim3(512), 0, stream,
                       x, b_1, b_2, ws, out);
}